// Round 1
// 229.001 us; speedup vs baseline: 1.0836x; 1.0836x over previous
//
#include <hip/hip_runtime.h>

static constexpr int HID = 32;
static constexpr int LEN = 32768;
static constexpr int NKL = 128;
static constexpr int HOP = 256;
#define SLOPE 0.2f

typedef short short8 __attribute__((ext_vector_type(8)));
typedef float floatx4 __attribute__((ext_vector_type(4)));
typedef unsigned int u32;

// ---------------- LDS map (main kernel), one __shared__ char arena ----------------
//   [0, 22400)       xs_t: 280 rows x 40 bf16 (80 B row)   [phase A..conv]
//                    ys_t: rows 0..271, same layout         [conv epi..LVC]
//                    os  : 32 rows x 264 bf16 (528 B row)   [post-LVC]
//   [22400, 35712)   b2: LVC weights [o(64)][104 bf16] (208 B row, cols 96..103 pad junk)
static constexpr int XROW  = 80;
static constexpr int WOFF  = 22400;
static constexpr int WROW  = 208;               // 104 bf16: kills the 8-way bank conflict
static constexpr int WSLAB = 64 * WROW;         // 13312 = 13 x 1024 -> exact gload_lds chunks
static constexpr int OSROW = 528;
static constexpr int SMEMB = WOFF + WSLAB;      // 35712 -> 4 blocks/CU (<= 40960)

// ---------------- workspace layout (ushort elements) ----------------
// kt  [16][128][64][104] bf16  = pre-transposed LVC weights (b2 LDS image per (b,kl))
// cwt [32][96] bf16            = conv weights in b1 fragment order
// ws bytes needed: (KT_USH + 3072)*2 ~= 26.1 MB
static constexpr size_t KT_USH  = (size_t)16 * NKL * 64 * 104;
static constexpr size_t CWT_OFF = KT_USH;

__device__ __forceinline__ float leaky(float x) { return fmaxf(x, SLOPE * x); }

__device__ __forceinline__ unsigned short f2bf(float f) {
    union { float f; unsigned u; } v; v.f = f;
    unsigned r = v.u + 0x7FFFu + ((v.u >> 16) & 1u);   // RNE
    return (unsigned short)(r >> 16);
}
__device__ __forceinline__ float bf2f(unsigned short s) {
    union { unsigned u; float f; } v; v.u = ((unsigned)s) << 16;
    return v.f;
}
// packed f32x2 -> bf16x2, RNE (same rounding as f2bf) in ONE VALU op
__device__ __forceinline__ u32 cvtpk(float lo, float hi) {
    u32 r;
    asm("v_cvt_pk_bf16_f32 %0, %1, %2" : "=v"(r) : "v"(lo), "v"(hi));
    return r;
}
__device__ __forceinline__ float gatef(float a, float c) {
    c = fminf(fmaxf(c, -20.0f), 20.0f);
    float sg = 1.0f / (1.0f + __expf(-a));
    float e2 = __expf(-2.0f * c);
    return sg * (1.0f - e2) / (1.0f + e2);
}

// =====================================================================================
// Pre-pass: transpose kern [b][i][o][k][kl] (f32, kl innermost) -> kt [b][kl][o][k*32+i]
// (bf16, 104-col padded rows). Converts the main kernel's 12.6M scattered line-requests
// into one coalesced 13KB global_load_lds slab per block. Also drops conv_w into
// fragment order (cwt). Pure-BW kernel: reads 50 MB coalesced, writes 26 MB in 192 B
// chunks (3 full lines each).
// =====================================================================================
__global__ __launch_bounds__(256) void prep_kern(
    const float* __restrict__ kern,    // [16][32][64][3][128]
    const float* __restrict__ cw,      // [32][32][3]
    unsigned short* __restrict__ kt)   // workspace
{
    const int blk = blockIdx.x;        // 1024 = b*64 + o
    const int b = blk >> 6, o = blk & 63;
    const int tid = threadIdx.x;
    __shared__ unsigned short lt[32 * 384];    // [i][kk*128 + kl] bf16, 24576 B

    // coalesced load of the (b,o) slice: per i, 384 contiguous floats
    const float* src = kern + (size_t)(b * 2048 + o) * 384;   // + i*24576 + kk*128 + kl
    #pragma unroll
    for (int j = 0; j < 12; ++j) {
        const int f = tid + 256 * j;           // float4 id < 3072
        const int i = f / 96, r = f - i * 96;
        float4 v = *(const float4*)(src + (size_t)i * 24576 + (size_t)r * 4);
        uint2 pk2 = make_uint2(cvtpk(v.x, v.y), cvtpk(v.z, v.w));
        *(uint2*)(lt + i * 384 + r * 4) = pk2;
    }

    if (blk == 0) {   // conv weights -> cwt[o2][kk*32+i]  (dest index == d)
        #pragma unroll
        for (int j = 0; j < 12; ++j) {
            const int d = tid + 256 * j;       // < 3072
            const int o2 = d / 96, rr = d - o2 * 96;
            const int kk = rr >> 5, i = rr & 31;
            kt[CWT_OFF + d] = f2bf(cw[(o2 * 32 + i) * 3 + kk]);
        }
    }
    __syncthreads();

    // transposed write-out: thread = (kl, half); 96 B contiguous per thread
    const int kl = tid >> 1, half = tid & 1;
    u32 wbuf[24];
    #pragma unroll
    for (int m = 0; m < 24; ++m) {
        const int c0 = half * 48 + 2 * m;      // col pair (c0, c0+1), same kk always
        const int kk = c0 >> 5, i0 = c0 & 31;
        u32 lo = lt[i0 * 384 + kk * 128 + kl];
        u32 hi = lt[(i0 + 1) * 384 + kk * 128 + kl];
        wbuf[m] = lo | (hi << 16);
    }
    unsigned short* dst = kt + ((size_t)(b * NKL + kl) * 64 + o) * 104 + half * 48;
    #pragma unroll
    for (int m = 0; m < 6; ++m)
        ((uint4*)dst)[m] = make_uint4(wbuf[4*m], wbuf[4*m+1], wbuf[4*m+2], wbuf[4*m+3]);
}

// =====================================================================================
// Main kernel
// =====================================================================================
__global__ __launch_bounds__(256, 3) void univnet_mfma(
    const float* __restrict__ h,      // [16][32][32768]
    const float* __restrict__ bias,   // [16][64][128]
    const float* __restrict__ cb,     // [32]
    float* __restrict__ out,
    const unsigned short* __restrict__ kt)   // ws: kt + cwt
{
    __shared__ __align__(16) char smem[SMEMB];

    const int blk = blockIdx.x;           // 2048
    const int b   = blk & 15;             // XCD-pinned: blk%8 == b%8
    const int kl  = blk >> 4;
    const int t0  = kl * HOP;
    const int p0  = t0 - 4;
    const int tid = threadIdx.x;
    const int w   = tid >> 6;
    const int lane = tid & 63;
    const int l15 = lane & 15;
    const int l4  = lane >> 4;

    const float* hb = h + (size_t)b * (HID * LEN);
    const bool edge = (kl == 0) || (kl == NKL - 1);

    // ---- async-stage LVC weight slab (pre-transposed, contiguous) into LDS ----
    // issued at entry; completes under phase A; s2's barrier drain guarantees visibility
    {
        const char* slab = (const char*)kt + (size_t)(b * NKL + kl) * WSLAB;
        #pragma unroll
        for (int j = 0; j < 4; ++j) {
            const int c = w + 4 * j;               // wave-uniform chunk id
            if (c < 13)
                __builtin_amdgcn_global_load_lds(
                    (const u32 __attribute__((address_space(1)))*)(slab + c * 1024 + lane * 16),
                    (u32 __attribute__((address_space(3)))*)(smem + WOFF + c * 1024),
                    16, 0, 0);
        }
    }

    // ---- prefetch conv-weight frags (regs, no LDS round-trip) + biases ----
    const unsigned short* cwt = kt + CWT_OFF;
    short8 b1f[2][3];
    #pragma unroll
    for (int tn = 0; tn < 2; ++tn)
        #pragma unroll
        for (int qk = 0; qk < 3; ++qk)
            b1f[tn][qk] = *(const short8*)(cwt + (tn * 16 + l15) * 96 + qk * 32 + l4 * 8);
    float4 cbq[2];                        // conv bias for swapped-C layout (ch = l4*4+r)
    cbq[0] = *(const float4*)(cb + l4 * 4);
    cbq[1] = *(const float4*)(cb + 16 + l4 * 4);
    float bv[2][2];                       // LVC bias, prefetched
    #pragma unroll
    for (int pp = 0; pp < 2; ++pp) {
        bv[pp][0] = bias[((size_t)b * 64 + pp * 16 + l15) * NKL + kl];
        bv[pp][1] = bias[((size_t)b * 64 + pp * 16 + l15 + 32) * NKL + kl];
    }

    // ================= Phase A: stage leaky(h) transposed (cvt_pk pairs) ============
    {
        auto stage = [&](int tau) {
            const int oct = tau & 3, cq = tau >> 2;
            u32 pk[4][4];                          // [e][jp]: channels (2jp, 2jp+1)
            if (!edge) {
                #pragma unroll
                for (int jp = 0; jp < 4; ++jp) {
                    const int i0 = oct * 8 + 2 * jp;
                    float4 f0 = *(const float4*)(hb + (size_t)i0 * LEN + p0 + 4 * cq);
                    float4 f1 = *(const float4*)(hb + (size_t)(i0 + 1) * LEN + p0 + 4 * cq);
                    pk[0][jp] = cvtpk(leaky(f0.x), leaky(f1.x));
                    pk[1][jp] = cvtpk(leaky(f0.y), leaky(f1.y));
                    pk[2][jp] = cvtpk(leaky(f0.z), leaky(f1.z));
                    pk[3][jp] = cvtpk(leaky(f0.w), leaky(f1.w));
                }
            } else {
                #pragma unroll
                for (int jp = 0; jp < 4; ++jp) {
                    const int i0 = oct * 8 + 2 * jp;
                    #pragma unroll
                    for (int e = 0; e < 4; ++e) {
                        const int p = p0 + 4 * cq + e;
                        float a = 0.0f, c2 = 0.0f;
                        if ((unsigned)p < (unsigned)LEN) {
                            a  = leaky(hb[(size_t)i0 * LEN + p]);
                            c2 = leaky(hb[(size_t)(i0 + 1) * LEN + p]);
                        }
                        pk[e][jp] = cvtpk(a, c2);
                    }
                }
            }
            #pragma unroll
            for (int e = 0; e < 4; ++e)
                *(uint4*)(smem + (4 * cq + e) * XROW + oct * 16) =
                    make_uint4(pk[e][0], pk[e][1], pk[e][2], pk[e][3]);
        };
        stage(tid);
        if (tid < 8) stage(256 + tid);
        // zero pad rows 264..279
        for (int z = tid; z < 320; z += 256)
            ((u32*)(smem + 264 * XROW))[z] = 0u;
    }

    __syncthreads();   // s0: xs_t ready

    // ================= Conv GEMM (operand-swapped => C^T layout) ====================
    // mfma(W, X): lane holds position = l15 (col), 4 consecutive channels (regs).
    floatx4 cacc[9];
    #pragma unroll
    for (int n = 0; n < 9; ++n) {
        const int tt = w + 4 * n;
        if (tt < 34) {
            const int tm = tt >> 1, tn = tt & 1;
            short8 af[3];
            #pragma unroll
            for (int qk = 0; qk < 3; ++qk)
                af[qk] = *(const short8*)(smem + (tm * 16 + l15 + 3 * qk) * XROW + l4 * 16);
            floatx4 acc = {cbq[tn].x, cbq[tn].y, cbq[tn].z, cbq[tn].w};
            #pragma unroll
            for (int qk = 0; qk < 3; ++qk)
                acc = __builtin_amdgcn_mfma_f32_16x16x32_bf16(b1f[tn][qk], af[qk], acc, 0, 0, 0);
            cacc[n] = acc;
        }
    }
    __syncthreads();   // s1: conv reads done; xs_t dead

    // ---- conv epilogue: one cvt_pk pair + one b64 store per tile (was 4x b16) ----
    #pragma unroll
    for (int n = 0; n < 9; ++n) {
        const int tt = w + 4 * n;
        if (tt < 34) {
            const int tm = tt >> 1, tn = tt & 1;
            const int c_out = tm * 16 + l15;
            const int p = t0 - 1 + c_out;
            u32 q0 = 0u, q1 = 0u;
            if ((unsigned)p < (unsigned)LEN) {
                q0 = cvtpk(leaky(cacc[n][0]), leaky(cacc[n][1]));
                q1 = cvtpk(leaky(cacc[n][2]), leaky(cacc[n][3]));
            }
            *(uint2*)(smem + c_out * XROW + (tn * 16 + l4 * 4) * 2) = make_uint2(q0, q1);
        }
    }
    __syncthreads();   // s2: ys_t ready; b2 slab long staged (drained at s0)

    // ================= LVC GEMM: [256 x 96] * [96 x 64], gate in-reg ================
    unsigned garr[2][4][2];
    #pragma unroll
    for (int pp = 0; pp < 2; ++pp) {
        const int oA = pp * 16 + l15, oB = oA + 32;
        short8 b2A[3], b2B[3];
        #pragma unroll
        for (int qk = 0; qk < 3; ++qk) {     // 208 B rows -> 2-way banked (free)
            b2A[qk] = *(const short8*)(smem + WOFF + oA * WROW + (qk * 32 + l4 * 8) * 2);
            b2B[qk] = *(const short8*)(smem + WOFF + oB * WROW + (qk * 32 + l4 * 8) * 2);
        }
        const float bA = bv[pp][0], bB = bv[pp][1];
        #pragma unroll
        for (int t = 0; t < 4; ++t) {
            const int tm = 4 * t + w;
            short8 af[3];
            #pragma unroll
            for (int qk = 0; qk < 3; ++qk)
                af[qk] = *(const short8*)(smem + (tm * 16 + l15 + qk) * XROW + l4 * 16);
            floatx4 aA = {bA, bA, bA, bA}, aB = {bB, bB, bB, bB};
            #pragma unroll
            for (int qk = 0; qk < 3; ++qk) {
                aA = __builtin_amdgcn_mfma_f32_16x16x32_bf16(af[qk], b2A[qk], aA, 0, 0, 0);
                aB = __builtin_amdgcn_mfma_f32_16x16x32_bf16(af[qk], b2B[qk], aB, 0, 0, 0);
            }
            #pragma unroll
            for (int hp = 0; hp < 2; ++hp)
                garr[pp][t][hp] =
                    cvtpk(gatef(aA[2 * hp], aB[2 * hp]), gatef(aA[2 * hp + 1], aB[2 * hp + 1]));
        }
    }
    __syncthreads();   // s3: LVC reads done; ys_t dead

    // ---- scatter gates to os[o][s] (bf16) ----
    #pragma unroll
    for (int pp = 0; pp < 2; ++pp) {
        const int o = pp * 16 + l15;
        #pragma unroll
        for (int t = 0; t < 4; ++t) {
            const int sbase = (4 * t + w) * 16 + l4 * 4;
            #pragma unroll
            for (int hp = 0; hp < 2; ++hp)
                *(u32*)(smem + o * OSROW + (sbase + 2 * hp) * 2) = garr[pp][t][hp];
        }
    }
    __syncthreads();   // s4

    // ================= Epilogue: out = h + gate, coalesced ================
    {
        const int eo = tid >> 3, e8 = tid & 7;
        const float* hrow = hb + (size_t)eo * LEN + t0;
        float* orow = out + ((size_t)b * HID + eo) * LEN + t0;
        #pragma unroll
        for (int rep = 0; rep < 8; ++rep) {
            const int s = e8 * 4 + 32 * rep;
            uint2 g = *(const uint2*)(smem + eo * OSROW + s * 2);
            float4 hv = *(const float4*)(hrow + s);
            float4 ov;
            ov.x = hv.x + bf2f((unsigned short)(g.x & 0xffff));
            ov.y = hv.y + bf2f((unsigned short)(g.x >> 16));
            ov.z = hv.z + bf2f((unsigned short)(g.y & 0xffff));
            ov.w = hv.w + bf2f((unsigned short)(g.y >> 16));
            *(float4*)(orow + s) = ov;
        }
    }
}

extern "C" void kernel_launch(void* const* d_in, const int* in_sizes, int n_in,
                              void* d_out, int out_size, void* d_ws, size_t ws_size,
                              hipStream_t stream) {
    const float* h    = (const float*)d_in[0];
    const float* kern = (const float*)d_in[1];
    const float* bias = (const float*)d_in[2];
    const float* cw   = (const float*)d_in[3];
    const float* cb   = (const float*)d_in[4];
    float* outp = (float*)d_out;
    unsigned short* kt = (unsigned short*)d_ws;   // needs ~26.1 MB workspace

    prep_kern<<<1024, 256, 0, stream>>>(kern, cw, kt);
    univnet_mfma<<<2048, 256, 0, stream>>>(h, bias, cb, outp, kt);
}

// Round 2
// 221.173 us; speedup vs baseline: 1.1219x; 1.0354x over previous
//
#include <hip/hip_runtime.h>

static constexpr int HID = 32;
static constexpr int LEN = 32768;
static constexpr int NKL = 128;
static constexpr int HOP = 256;
#define SLOPE 0.2f

typedef short short8 __attribute__((ext_vector_type(8)));
typedef float floatx4 __attribute__((ext_vector_type(4)));
typedef unsigned int u32;

// ---------------- LDS map (main kernel), one __shared__ char arena ----------------
//   [0, 17792)       xs_t: 278 rows x 64 B (32 bf16), XOR-swizzled (row&7)<<4
//                    ys_t: rows 0..273, same layout/swizzle   [conv epi..LVC]
//                    os  : 32 rows x 264 bf16 (528 B row), linear [post-LVC]
//   [17792, 31104)   b2: LVC weights [o(64)][104 bf16] (208 B row), linear
static constexpr int XROW  = 64;
static constexpr int WOFF  = 17792;             // = 278 * 64
static constexpr int WROW  = 208;               // 104 bf16 -> 2-way banked reads (free)
static constexpr int WSLAB = 64 * WROW;         // 13312 = 13 x 1024 gload_lds chunks
static constexpr int OSROW = 528;
static constexpr int SMEMB = WOFF + WSLAB;      // 31104 -> 5 blocks/CU

// xs_t/ys_t byte address: bijective XOR swizzle, conflict-free for row=f(l15) reads
__device__ __forceinline__ int xsw(int row, int bcol) {
    return ((row << 6) + bcol) ^ ((row & 7) << 4);
}

// ---------------- workspace layout (ushort elements) ----------------
static constexpr size_t KT_USH  = (size_t)16 * NKL * 64 * 104;
static constexpr size_t CWT_OFF = KT_USH;

__device__ __forceinline__ float leaky(float x) { return fmaxf(x, SLOPE * x); }

__device__ __forceinline__ unsigned short f2bf(float f) {
    union { float f; unsigned u; } v; v.f = f;
    unsigned r = v.u + 0x7FFFu + ((v.u >> 16) & 1u);   // RNE
    return (unsigned short)(r >> 16);
}
__device__ __forceinline__ float bf2f(unsigned short s) {
    union { unsigned u; float f; } v; v.u = ((unsigned)s) << 16;
    return v.f;
}
__device__ __forceinline__ u32 cvtpk(float lo, float hi) {
    u32 r;
    asm("v_cvt_pk_bf16_f32 %0, %1, %2" : "=v"(r) : "v"(lo), "v"(hi));
    return r;
}
__device__ __forceinline__ float rcp_fast(float x) {   // 1 ulp, inf->0 (exact limit)
    float r; asm("v_rcp_f32 %0, %1" : "=v"(r) : "v"(x)); return r;
}
// sigmoid(a)*tanh(c): tanh via 1 - 2/(1+e^{2c}); saturates correctly at +-inf
__device__ __forceinline__ float gatef(float a, float c) {
    float sg = rcp_fast(1.0f + __expf(-a));
    float t  = fmaf(-2.0f, rcp_fast(1.0f + __expf(2.0f * c)), 1.0f);
    return sg * t;
}

// =====================================================================================
// Pre-pass (unchanged from R1): kern [b][i][o][k][kl] f32 -> kt [b][kl][o][104] bf16
// =====================================================================================
__global__ __launch_bounds__(256) void prep_kern(
    const float* __restrict__ kern,    // [16][32][64][3][128]
    const float* __restrict__ cw,      // [32][32][3]
    unsigned short* __restrict__ kt)   // workspace
{
    const int blk = blockIdx.x;        // 1024 = b*64 + o
    const int b = blk >> 6, o = blk & 63;
    const int tid = threadIdx.x;
    __shared__ unsigned short lt[32 * 384];    // [i][kk*128 + kl] bf16

    const float* src = kern + (size_t)(b * 2048 + o) * 384;
    #pragma unroll
    for (int j = 0; j < 12; ++j) {
        const int f = tid + 256 * j;
        const int i = f / 96, r = f - i * 96;
        float4 v = *(const float4*)(src + (size_t)i * 24576 + (size_t)r * 4);
        uint2 pk2 = make_uint2(cvtpk(v.x, v.y), cvtpk(v.z, v.w));
        *(uint2*)(lt + i * 384 + r * 4) = pk2;
    }

    if (blk == 0) {   // conv weights -> cwt[o2][kk*32+i]
        #pragma unroll
        for (int j = 0; j < 12; ++j) {
            const int d = tid + 256 * j;
            const int o2 = d / 96, rr = d - o2 * 96;
            const int kk = rr >> 5, i = rr & 31;
            kt[CWT_OFF + d] = f2bf(cw[(o2 * 32 + i) * 3 + kk]);
        }
    }
    __syncthreads();

    const int kl = tid >> 1, half = tid & 1;
    u32 wbuf[24];
    #pragma unroll
    for (int m = 0; m < 24; ++m) {
        const int c0 = half * 48 + 2 * m;
        const int kk = c0 >> 5, i0 = c0 & 31;
        u32 lo = lt[i0 * 384 + kk * 128 + kl];
        u32 hi = lt[(i0 + 1) * 384 + kk * 128 + kl];
        wbuf[m] = lo | (hi << 16);
    }
    unsigned short* dst = kt + ((size_t)(b * NKL + kl) * 64 + o) * 104 + half * 48;
    #pragma unroll
    for (int m = 0; m < 6; ++m)
        ((uint4*)dst)[m] = make_uint4(wbuf[4*m], wbuf[4*m+1], wbuf[4*m+2], wbuf[4*m+3]);
}

// =====================================================================================
// Main kernel
// =====================================================================================
__global__ __launch_bounds__(256, 5) void univnet_mfma(
    const float* __restrict__ h,      // [16][32][32768]
    const float* __restrict__ bias,   // [16][64][128]
    const float* __restrict__ cb,     // [32]
    float* __restrict__ out,
    const unsigned short* __restrict__ kt)
{
    __shared__ __align__(16) char smem[SMEMB];

    const int blk = blockIdx.x;           // 2048
    const int b   = blk & 15;             // XCD-pinned: blk%8 == b%8
    const int kl  = blk >> 4;
    const int t0  = kl * HOP;
    const int p0  = t0 - 4;
    const int tid = threadIdx.x;
    const int w   = tid >> 6;
    const int lane = tid & 63;
    const int l15 = lane & 15;
    const int l4  = lane >> 4;

    const float* hb = h + (size_t)b * (HID * LEN);
    const bool edge = (kl == 0) || (kl == NKL - 1);

    // ---- async-stage LVC weight slab into LDS (linear dest, drained at s0) ----
    {
        const char* slab = (const char*)kt + (size_t)(b * NKL + kl) * WSLAB;
        #pragma unroll
        for (int j = 0; j < 4; ++j) {
            const int c = w + 4 * j;
            if (c < 13)
                __builtin_amdgcn_global_load_lds(
                    (const u32 __attribute__((address_space(1)))*)(slab + c * 1024 + lane * 16),
                    (u32 __attribute__((address_space(3)))*)(smem + WOFF + c * 1024),
                    16, 0, 0);
        }
    }

    // ---- prefetch conv-weight frags + biases ----
    const unsigned short* cwt = kt + CWT_OFF;
    short8 b1f[2][3];
    #pragma unroll
    for (int tn = 0; tn < 2; ++tn)
        #pragma unroll
        for (int qk = 0; qk < 3; ++qk)
            b1f[tn][qk] = *(const short8*)(cwt + (tn * 16 + l15) * 96 + qk * 32 + l4 * 8);
    float4 cbq[2];
    cbq[0] = *(const float4*)(cb + l4 * 4);
    cbq[1] = *(const float4*)(cb + 16 + l4 * 4);
    float bv[2][2];
    #pragma unroll
    for (int pp = 0; pp < 2; ++pp) {
        bv[pp][0] = bias[((size_t)b * 64 + pp * 16 + l15) * NKL + kl];
        bv[pp][1] = bias[((size_t)b * 64 + pp * 16 + l15 + 32) * NKL + kl];
    }

    // ================= Phase A: stage leaky(h) transposed, swizzled ================
    {
        auto stage = [&](int tau) {
            const int oct = tau & 3, cq = tau >> 2;
            u32 pk[4][4];
            if (!edge) {
                #pragma unroll
                for (int jp = 0; jp < 4; ++jp) {
                    const int i0 = oct * 8 + 2 * jp;
                    float4 f0 = *(const float4*)(hb + (size_t)i0 * LEN + p0 + 4 * cq);
                    float4 f1 = *(const float4*)(hb + (size_t)(i0 + 1) * LEN + p0 + 4 * cq);
                    pk[0][jp] = cvtpk(leaky(f0.x), leaky(f1.x));
                    pk[1][jp] = cvtpk(leaky(f0.y), leaky(f1.y));
                    pk[2][jp] = cvtpk(leaky(f0.z), leaky(f1.z));
                    pk[3][jp] = cvtpk(leaky(f0.w), leaky(f1.w));
                }
            } else {
                #pragma unroll
                for (int jp = 0; jp < 4; ++jp) {
                    const int i0 = oct * 8 + 2 * jp;
                    #pragma unroll
                    for (int e = 0; e < 4; ++e) {
                        const int p = p0 + 4 * cq + e;
                        float a = 0.0f, c2 = 0.0f;
                        if ((unsigned)p < (unsigned)LEN) {
                            a  = leaky(hb[(size_t)i0 * LEN + p]);
                            c2 = leaky(hb[(size_t)(i0 + 1) * LEN + p]);
                        }
                        pk[e][jp] = cvtpk(a, c2);
                    }
                }
            }
            #pragma unroll
            for (int e = 0; e < 4; ++e)
                *(uint4*)(smem + xsw(4 * cq + e, oct * 16)) =
                    make_uint4(pk[e][0], pk[e][1], pk[e][2], pk[e][3]);
        };
        stage(tid);
        if (tid < 8) stage(256 + tid);
        // zero pad rows 264..277 (bytes [16896, 17792))
        if (tid < 224) ((u32*)(smem + 16896))[tid] = 0u;
    }

    __syncthreads();   // s0: xs_t + b2 slab ready

    // ================= Conv GEMM (operand-swapped => C^T layout) ====================
    floatx4 cacc[9];
    #pragma unroll
    for (int n = 0; n < 9; ++n) {
        const int tt = w + 4 * n;
        if (tt < 34) {
            const int tm = tt >> 1, tn = tt & 1;
            short8 af[3];
            #pragma unroll
            for (int qk = 0; qk < 3; ++qk)
                af[qk] = *(const short8*)(smem + xsw(tm * 16 + l15 + 3 * qk, l4 * 16));
            floatx4 acc = {cbq[tn].x, cbq[tn].y, cbq[tn].z, cbq[tn].w};
            #pragma unroll
            for (int qk = 0; qk < 3; ++qk)
                acc = __builtin_amdgcn_mfma_f32_16x16x32_bf16(b1f[tn][qk], af[qk], acc, 0, 0, 0);
            cacc[n] = acc;
        }
    }
    __syncthreads();   // s1: conv reads done; xs_t dead

    // ---- conv epilogue: cvt_pk pair + one 8-B store per tile, swizzled ----
    #pragma unroll
    for (int n = 0; n < 9; ++n) {
        const int tt = w + 4 * n;
        if (tt < 34) {
            const int tm = tt >> 1, tn = tt & 1;
            const int c_out = tm * 16 + l15;
            const int p = t0 - 1 + c_out;
            u32 q0 = 0u, q1 = 0u;
            if ((unsigned)p < (unsigned)LEN) {
                q0 = cvtpk(leaky(cacc[n][0]), leaky(cacc[n][1]));
                q1 = cvtpk(leaky(cacc[n][2]), leaky(cacc[n][3]));
            }
            *(uint2*)(smem + xsw(c_out, tn * 32 + l4 * 8)) = make_uint2(q0, q1);
        }
    }
    __syncthreads();   // s2: ys_t ready

    // ================= LVC GEMM: [256 x 96] * [96 x 64], gate in-reg ================
    unsigned garr[2][4][2];
    #pragma unroll
    for (int pp = 0; pp < 2; ++pp) {
        const int oA = pp * 16 + l15, oB = oA + 32;
        short8 b2A[3], b2B[3];
        #pragma unroll
        for (int qk = 0; qk < 3; ++qk) {
            b2A[qk] = *(const short8*)(smem + WOFF + oA * WROW + (qk * 32 + l4 * 8) * 2);
            b2B[qk] = *(const short8*)(smem + WOFF + oB * WROW + (qk * 32 + l4 * 8) * 2);
        }
        const float bA = bv[pp][0], bB = bv[pp][1];
        #pragma unroll
        for (int t = 0; t < 4; ++t) {
            const int tm = 4 * t + w;
            short8 af[3];
            #pragma unroll
            for (int qk = 0; qk < 3; ++qk)
                af[qk] = *(const short8*)(smem + xsw(tm * 16 + l15 + qk, l4 * 16));
            floatx4 aA = {bA, bA, bA, bA}, aB = {bB, bB, bB, bB};
            #pragma unroll
            for (int qk = 0; qk < 3; ++qk) {
                aA = __builtin_amdgcn_mfma_f32_16x16x32_bf16(af[qk], b2A[qk], aA, 0, 0, 0);
                aB = __builtin_amdgcn_mfma_f32_16x16x32_bf16(af[qk], b2B[qk], aB, 0, 0, 0);
            }
            #pragma unroll
            for (int hp = 0; hp < 2; ++hp)
                garr[pp][t][hp] =
                    cvtpk(gatef(aA[2 * hp], aB[2 * hp]), gatef(aA[2 * hp + 1], aB[2 * hp + 1]));
        }
    }
    __syncthreads();   // s3: LVC reads done; ys_t dead

    // ---- scatter gates to os[o][s] (bf16, linear) ----
    #pragma unroll
    for (int pp = 0; pp < 2; ++pp) {
        const int o = pp * 16 + l15;
        #pragma unroll
        for (int t = 0; t < 4; ++t) {
            const int sbase = (4 * t + w) * 16 + l4 * 4;
            #pragma unroll
            for (int hp = 0; hp < 2; ++hp)
                *(u32*)(smem + o * OSROW + (sbase + 2 * hp) * 2) = garr[pp][t][hp];
        }
    }
    __syncthreads();   // s4

    // ================= Epilogue: out = h + gate, coalesced ================
    {
        const int eo = tid >> 3, e8 = tid & 7;
        const float* hrow = hb + (size_t)eo * LEN + t0;
        float* orow = out + ((size_t)b * HID + eo) * LEN + t0;
        #pragma unroll
        for (int rep = 0; rep < 8; ++rep) {
            const int s = e8 * 4 + 32 * rep;
            uint2 g = *(const uint2*)(smem + eo * OSROW + s * 2);
            float4 hv = *(const float4*)(hrow + s);
            float4 ov;
            ov.x = hv.x + bf2f((unsigned short)(g.x & 0xffff));
            ov.y = hv.y + bf2f((unsigned short)(g.x >> 16));
            ov.z = hv.z + bf2f((unsigned short)(g.y & 0xffff));
            ov.w = hv.w + bf2f((unsigned short)(g.y >> 16));
            *(float4*)(orow + s) = ov;
        }
    }
}

extern "C" void kernel_launch(void* const* d_in, const int* in_sizes, int n_in,
                              void* d_out, int out_size, void* d_ws, size_t ws_size,
                              hipStream_t stream) {
    const float* h    = (const float*)d_in[0];
    const float* kern = (const float*)d_in[1];
    const float* bias = (const float*)d_in[2];
    const float* cw   = (const float*)d_in[3];
    const float* cb   = (const float*)d_in[4];
    float* outp = (float*)d_out;
    unsigned short* kt = (unsigned short*)d_ws;   // ~26.1 MB workspace

    prep_kern<<<1024, 256, 0, stream>>>(kern, cw, kt);
    univnet_mfma<<<2048, 256, 0, stream>>>(h, bias, cb, outp, kt);
}